// Round 7
// baseline (140.651 us; speedup 1.0000x reference)
//
#include <hip/hip_runtime.h>
#include <hip/hip_fp16.h>

#define IN_F   100000
#define OUT_F  100000
#define NNZ_N  1600000
#define TC     256
#define TBLK   ((IN_F + TC - 1) / TC)      // 391 transpose blocks
#define SBLK   ((NNZ_N + 255) / 256)       // 6250 scan/pack blocks

__device__ __forceinline__ float2 h2f(unsigned u) {
    const __half2 h = *reinterpret_cast<const __half2*>(&u);
    return __half22float2(h);
}

// ---------------------------------------------------------------------------
// Prep (fused): blocks [0,TBLK) transpose x (64,IN) f32 -> xh (IN,64) f16
// (u32 index: col*32 + pair). Blocks [TBLK,TBLK+SBLK): rowstart linear scan
// over sorted rows + (col,val) -> uint2 pack. Streams marked nontemporal.
// ---------------------------------------------------------------------------
__global__ __launch_bounds__(256) void k_prep(
    const float* __restrict__ x,
    const int*   __restrict__ rows,
    const int*   __restrict__ cols,
    const float* __restrict__ vals,
    unsigned* __restrict__ xh,
    int*      __restrict__ rstart,
    unsigned long long* __restrict__ pairs) {
    __shared__ unsigned tile[TC][33];
    const int bid = blockIdx.x;
    const int t   = threadIdx.x;

    if (bid < TBLK) {
        const int i0   = bid * TC;
        const int colr = i0 + t;
        if (colr < IN_F) {
            #pragma unroll 8
            for (int p = 0; p < 32; ++p) {
                const float a = __builtin_nontemporal_load(&x[(size_t)(2 * p)     * IN_F + colr]);
                const float b = __builtin_nontemporal_load(&x[(size_t)(2 * p + 1) * IN_F + colr]);
                const __half2 h = __floats2half2_rn(a, b);
                tile[t][p] = *reinterpret_cast<const unsigned*>(&h);
            }
        }
        __syncthreads();
        const int u  = t & 31;
        const int c8 = t >> 5;
        for (int cc = c8; cc < TC; cc += 8) {
            const int col = i0 + cc;
            if (col < IN_F)
                xh[(size_t)col * 32 + u] = tile[cc][u];
        }
    } else {
        const int e = (bid - TBLK) * 256 + t;
        if (e >= NNZ_N) return;
        const int cur  = rows[e];
        const int prev = (e == 0) ? -1 : rows[e - 1];
        for (int r = prev + 1; r <= cur; ++r) rstart[r] = e;
        if (e == NNZ_N - 1)
            for (int r = cur + 1; r <= OUT_F; ++r) rstart[r] = NNZ_N;
        const unsigned long long pv =
            (unsigned)cols[e] | ((unsigned long long)__float_as_uint(vals[e]) << 32);
        __builtin_nontemporal_store(pv, &pairs[e]);
    }
}

// ---------------------------------------------------------------------------
// SpMM (R5 structure — measured best): block = 512 threads = 8 waves = 64
// rows. Each 8-lane group owns ONE row; lane sub in [0,8) loads uint4 = 8
// halves = batches 8sub..8sub+7. One wave-instruction = 8 distinct edges;
// unroll-4 -> 32 lines in flight per wave. Streams (pairs, out) are
// nontemporal so L2 retains xh gather lines.
// ---------------------------------------------------------------------------
__global__ __launch_bounds__(512, 4) void k_spmm(
    const uint4* __restrict__ xh4,        // col*8 + sub
    const unsigned long long* __restrict__ pairs,
    const int*   __restrict__ rstart_g,
    const float* __restrict__ bias,
    float* __restrict__ out) {
    __shared__ int   rs[65];
    __shared__ float tile[64][65];
    const int r0   = blockIdx.x * 64;
    const int t    = threadIdx.x;
    const int lane = t & 63;
    const int w    = t >> 6;

    if (t < 65) {
        int idx = r0 + t; if (idx > OUT_F) idx = OUT_F;
        rs[t] = rstart_g[idx];
    }
    __syncthreads();

    const int g   = lane >> 3;            // group -> local row
    const int sub = lane & 7;             // batch octet
    const int lj  = (w << 3) + g;
    const int s   = rs[lj];
    const int e   = rs[lj + 1];

    float acc[8];
    #pragma unroll
    for (int i = 0; i < 8; ++i) acc[i] = 0.f;

    for (int base = s; base < e; base += 4) {
        const int e1 = e - 1;
        const int i1 = (base + 1 < e) ? base + 1 : e1;
        const int i2 = (base + 2 < e) ? base + 2 : e1;
        const int i3 = (base + 3 < e) ? base + 3 : e1;
        const unsigned long long q0 = __builtin_nontemporal_load(&pairs[base]);
        const unsigned long long q1 = __builtin_nontemporal_load(&pairs[i1]);
        const unsigned long long q2 = __builtin_nontemporal_load(&pairs[i2]);
        const unsigned long long q3 = __builtin_nontemporal_load(&pairs[i3]);
        const unsigned c0 = (unsigned)q0, c1 = (unsigned)q1;
        const unsigned c2 = (unsigned)q2, c3 = (unsigned)q3;
        const float v0 = __uint_as_float((unsigned)(q0 >> 32));
        const float v1 = (base + 1 < e) ? __uint_as_float((unsigned)(q1 >> 32)) : 0.f;
        const float v2 = (base + 2 < e) ? __uint_as_float((unsigned)(q2 >> 32)) : 0.f;
        const float v3 = (base + 3 < e) ? __uint_as_float((unsigned)(q3 >> 32)) : 0.f;
        const uint4 u0 = xh4[(size_t)c0 * 8 + sub];
        const uint4 u1 = xh4[(size_t)c1 * 8 + sub];
        const uint4 u2 = xh4[(size_t)c2 * 8 + sub];
        const uint4 u3 = xh4[(size_t)c3 * 8 + sub];
        float2 f;
        f = h2f(u0.x); acc[0] = fmaf(v0, f.x, acc[0]); acc[1] = fmaf(v0, f.y, acc[1]);
        f = h2f(u0.y); acc[2] = fmaf(v0, f.x, acc[2]); acc[3] = fmaf(v0, f.y, acc[3]);
        f = h2f(u0.z); acc[4] = fmaf(v0, f.x, acc[4]); acc[5] = fmaf(v0, f.y, acc[5]);
        f = h2f(u0.w); acc[6] = fmaf(v0, f.x, acc[6]); acc[7] = fmaf(v0, f.y, acc[7]);
        f = h2f(u1.x); acc[0] = fmaf(v1, f.x, acc[0]); acc[1] = fmaf(v1, f.y, acc[1]);
        f = h2f(u1.y); acc[2] = fmaf(v1, f.x, acc[2]); acc[3] = fmaf(v1, f.y, acc[3]);
        f = h2f(u1.z); acc[4] = fmaf(v1, f.x, acc[4]); acc[5] = fmaf(v1, f.y, acc[5]);
        f = h2f(u1.w); acc[6] = fmaf(v1, f.x, acc[6]); acc[7] = fmaf(v1, f.y, acc[7]);
        f = h2f(u2.x); acc[0] = fmaf(v2, f.x, acc[0]); acc[1] = fmaf(v2, f.y, acc[1]);
        f = h2f(u2.y); acc[2] = fmaf(v2, f.x, acc[2]); acc[3] = fmaf(v2, f.y, acc[3]);
        f = h2f(u2.z); acc[4] = fmaf(v2, f.x, acc[4]); acc[5] = fmaf(v2, f.y, acc[5]);
        f = h2f(u2.w); acc[6] = fmaf(v2, f.x, acc[6]); acc[7] = fmaf(v2, f.y, acc[7]);
        f = h2f(u3.x); acc[0] = fmaf(v3, f.x, acc[0]); acc[1] = fmaf(v3, f.y, acc[1]);
        f = h2f(u3.y); acc[2] = fmaf(v3, f.x, acc[2]); acc[3] = fmaf(v3, f.y, acc[3]);
        f = h2f(u3.z); acc[4] = fmaf(v3, f.x, acc[4]); acc[5] = fmaf(v3, f.y, acc[5]);
        f = h2f(u3.w); acc[6] = fmaf(v3, f.x, acc[6]); acc[7] = fmaf(v3, f.y, acc[7]);
    }

    #pragma unroll
    for (int i = 0; i < 8; ++i) tile[lj][(sub << 3) + i] = acc[i];
    __syncthreads();

    const int rc = r0 + lane;
    if (rc < OUT_F) {
        const float bv = bias[rc];
        for (int bb = w; bb < 64; bb += 8)
            __builtin_nontemporal_store(tile[lane][bb] + bv,
                                        &out[(size_t)bb * OUT_F + rc]);
    }
}

// ---------------------------------------------------------------------------
// Fallback (insufficient ws): gather from native x layout. Correct, slow.
// ---------------------------------------------------------------------------
__global__ __launch_bounds__(256) void k_spmm_fallback(
    const float* __restrict__ x,
    const float* __restrict__ vals,
    const int*   __restrict__ rows,
    const int*   __restrict__ cols,
    const float* __restrict__ bias,
    float* __restrict__ out) {
    __shared__ int   rstart[65];
    __shared__ float tile[64][65];
    const int r0   = blockIdx.x * 64;
    const int t    = threadIdx.x;
    const int lane = t & 63;
    const int w    = t >> 6;
    if (t < 65) {
        const int target = r0 + t;
        int lo = 0, hi = NNZ_N;
        while (lo < hi) {
            const int mid = (lo + hi) >> 1;
            if (rows[mid] < target) lo = mid + 1; else hi = mid;
        }
        rstart[t] = lo;
    }
    __syncthreads();
    for (int j = w; j < 64; j += 4) {
        const int s = rstart[j], e = rstart[j + 1];
        float acc = 0.f;
        const size_t base = (size_t)lane * IN_F;
        for (int idx = s; idx < e; ++idx)
            acc = fmaf(vals[idx], x[base + cols[idx]], acc);
        tile[j][lane] = acc;
    }
    __syncthreads();
    const int c = lane;
    if (r0 + c < OUT_F) {
        const float bv = bias[r0 + c];
        for (int bb = w; bb < 64; bb += 4)
            out[(size_t)bb * OUT_F + (r0 + c)] = tile[c][bb] + bv;
    }
}

extern "C" void kernel_launch(void* const* d_in, const int* in_sizes, int n_in,
                              void* d_out, int out_size, void* d_ws, size_t ws_size,
                              hipStream_t stream) {
    const float* x      = (const float*)d_in[0];
    const float* values = (const float*)d_in[1];
    const float* bias   = (const float*)d_in[2];
    const int*   rows   = (const int*)d_in[3];
    const int*   cols   = (const int*)d_in[4];
    float*       out    = (float*)d_out;

    const size_t xh_bytes = (size_t)IN_F * 32 * sizeof(unsigned);   // 12.8 MB
    const size_t rs_off   = (xh_bytes + 255) & ~(size_t)255;
    const size_t rs_bytes = (size_t)(OUT_F + 1) * sizeof(int);
    const size_t pr_off   = (rs_off + rs_bytes + 255) & ~(size_t)255;
    const size_t need     = pr_off + (size_t)NNZ_N * sizeof(unsigned long long);

    const int row_blocks = (OUT_F + 63) / 64;   // 1563

    if (ws_size >= need) {
        unsigned* xh     = (unsigned*)d_ws;
        int*      rstart = (int*)((char*)d_ws + rs_off);
        unsigned long long* pairs = (unsigned long long*)((char*)d_ws + pr_off);
        k_prep<<<TBLK + SBLK, 256, 0, stream>>>(x, rows, cols, values, xh, rstart, pairs);
        k_spmm<<<row_blocks, 512, 0, stream>>>(
            (const uint4*)xh, pairs, rstart, bias, out);
    } else {
        k_spmm_fallback<<<row_blocks, 256, 0, stream>>>(x, values, rows, cols, bias, out);
    }
}

// Round 8
// 135.025 us; speedup vs baseline: 1.0417x; 1.0417x over previous
//
#include <hip/hip_runtime.h>
#include <hip/hip_fp16.h>

#define IN_F   100000
#define OUT_F  100000
#define NNZ_N  1600000
#define TC     256
#define TBLK   ((IN_F + TC - 1) / TC)      // 391 transpose blocks
#define SBLK   ((NNZ_N + 255) / 256)       // 6250 scan/pack blocks

__device__ __forceinline__ float2 h2f(unsigned u) {
    const __half2 h = *reinterpret_cast<const __half2*>(&u);
    return __half22float2(h);
}

// ---------------------------------------------------------------------------
// Prep (fused, R5-identical): blocks [0,TBLK) transpose x (64,IN) f32 ->
// xh (IN,64) f16 (u32 index: col*32 + pair). Blocks [TBLK,TBLK+SBLK):
// rowstart linear scan over sorted rows + (col,val) -> uint2 pack.
// ---------------------------------------------------------------------------
__global__ __launch_bounds__(256) void k_prep(
    const float* __restrict__ x,
    const int*   __restrict__ rows,
    const int*   __restrict__ cols,
    const float* __restrict__ vals,
    unsigned* __restrict__ xh,
    int*      __restrict__ rstart,
    uint2*    __restrict__ pairs) {
    __shared__ unsigned tile[TC][33];
    const int bid = blockIdx.x;
    const int t   = threadIdx.x;

    if (bid < TBLK) {
        const int i0   = bid * TC;
        const int colr = i0 + t;
        if (colr < IN_F) {
            #pragma unroll 8
            for (int p = 0; p < 32; ++p) {
                const float a = x[(size_t)(2 * p)     * IN_F + colr];
                const float b = x[(size_t)(2 * p + 1) * IN_F + colr];
                const __half2 h = __floats2half2_rn(a, b);
                tile[t][p] = *reinterpret_cast<const unsigned*>(&h);
            }
        }
        __syncthreads();
        const int u  = t & 31;
        const int c8 = t >> 5;
        for (int cc = c8; cc < TC; cc += 8) {
            const int col = i0 + cc;
            if (col < IN_F)
                xh[(size_t)col * 32 + u] = tile[cc][u];
        }
    } else {
        const int e = (bid - TBLK) * 256 + t;
        if (e >= NNZ_N) return;
        const int cur  = rows[e];
        const int prev = (e == 0) ? -1 : rows[e - 1];
        for (int r = prev + 1; r <= cur; ++r) rstart[r] = e;
        if (e == NNZ_N - 1)
            for (int r = cur + 1; r <= OUT_F; ++r) rstart[r] = NNZ_N;
        pairs[e] = make_uint2((unsigned)cols[e], __float_as_uint(vals[e]));
    }
}

// ---------------------------------------------------------------------------
// SpMM: block = 512 threads = 8 waves = 64 groups; each 8-lane group owns
// TWO consecutive rows as ONE contiguous edge range [rs[2g], rs[2g+2])
// (rows sorted => contiguous), attributing each edge to acc0/acc1 by
// comparing edge index to the split rs[2g+1] (branchless multiplier
// select). Halves relative intra-wave tail imbalance while keeping R5's
// gather issue structure: 8 lanes/edge x uint4, unroll-4 = 32 lines in
// flight per wave. Block covers 128 rows.
// ---------------------------------------------------------------------------
__global__ __launch_bounds__(512, 4) void k_spmm(
    const uint4* __restrict__ xh4,        // col*8 + sub
    const uint2* __restrict__ pairs,
    const int*   __restrict__ rstart_g,
    const float* __restrict__ bias,
    float* __restrict__ out) {
    __shared__ int   rs[129];
    __shared__ float tile[128][65];
    const int r0   = blockIdx.x * 128;
    const int t    = threadIdx.x;
    const int lane = t & 63;
    const int w    = t >> 6;

    if (t < 129) {
        int idx = r0 + t; if (idx > OUT_F) idx = OUT_F;
        rs[t] = rstart_g[idx];
    }
    __syncthreads();

    const int g   = lane >> 3;            // group within wave [0,8)
    const int sub = lane & 7;             // batch octet
    const int gid = (w << 3) + g;         // [0,64)
    const int lj0 = gid << 1;             // two local rows lj0, lj0+1

    const int s = rs[lj0];
    const int m = rs[lj0 + 1];            // split between the two rows
    const int e = rs[lj0 + 2];

    float acc0[8], acc1[8];
    #pragma unroll
    for (int i = 0; i < 8; ++i) { acc0[i] = 0.f; acc1[i] = 0.f; }

    for (int base = s; base < e; base += 4) {
        const int eL = e - 1;
        const int i1 = (base + 1 < e) ? base + 1 : eL;
        const int i2 = (base + 2 < e) ? base + 2 : eL;
        const int i3 = (base + 3 < e) ? base + 3 : eL;
        const uint2 p0 = pairs[base];
        const uint2 p1 = pairs[i1];
        const uint2 p2 = pairs[i2];
        const uint2 p3 = pairs[i3];
        // raw values, zeroed past the range end
        const float v0 = __uint_as_float(p0.y);
        const float v1 = (base + 1 < e) ? __uint_as_float(p1.y) : 0.f;
        const float v2 = (base + 2 < e) ? __uint_as_float(p2.y) : 0.f;
        const float v3 = (base + 3 < e) ? __uint_as_float(p3.y) : 0.f;
        // row attribution: multiplier goes to acc0 if idx < m else acc1
        const float a0 = (base     < m) ? v0 : 0.f, b0 = (base     < m) ? 0.f : v0;
        const float a1 = (base + 1 < m) ? v1 : 0.f, b1 = (base + 1 < m) ? 0.f : v1;
        const float a2 = (base + 2 < m) ? v2 : 0.f, b2 = (base + 2 < m) ? 0.f : v2;
        const float a3 = (base + 3 < m) ? v3 : 0.f, b3 = (base + 3 < m) ? 0.f : v3;
        const uint4 u0 = xh4[(size_t)p0.x * 8 + sub];
        const uint4 u1 = xh4[(size_t)p1.x * 8 + sub];
        const uint4 u2 = xh4[(size_t)p2.x * 8 + sub];
        const uint4 u3 = xh4[(size_t)p3.x * 8 + sub];
        float2 f;
        f = h2f(u0.x); acc0[0] = fmaf(a0, f.x, acc0[0]); acc1[0] = fmaf(b0, f.x, acc1[0]);
                       acc0[1] = fmaf(a0, f.y, acc0[1]); acc1[1] = fmaf(b0, f.y, acc1[1]);
        f = h2f(u0.y); acc0[2] = fmaf(a0, f.x, acc0[2]); acc1[2] = fmaf(b0, f.x, acc1[2]);
                       acc0[3] = fmaf(a0, f.y, acc0[3]); acc1[3] = fmaf(b0, f.y, acc1[3]);
        f = h2f(u0.z); acc0[4] = fmaf(a0, f.x, acc0[4]); acc1[4] = fmaf(b0, f.x, acc1[4]);
                       acc0[5] = fmaf(a0, f.y, acc0[5]); acc1[5] = fmaf(b0, f.y, acc1[5]);
        f = h2f(u0.w); acc0[6] = fmaf(a0, f.x, acc0[6]); acc1[6] = fmaf(b0, f.x, acc1[6]);
                       acc0[7] = fmaf(a0, f.y, acc0[7]); acc1[7] = fmaf(b0, f.y, acc1[7]);
        f = h2f(u1.x); acc0[0] = fmaf(a1, f.x, acc0[0]); acc1[0] = fmaf(b1, f.x, acc1[0]);
                       acc0[1] = fmaf(a1, f.y, acc0[1]); acc1[1] = fmaf(b1, f.y, acc1[1]);
        f = h2f(u1.y); acc0[2] = fmaf(a1, f.x, acc0[2]); acc1[2] = fmaf(b1, f.x, acc1[2]);
                       acc0[3] = fmaf(a1, f.y, acc0[3]); acc1[3] = fmaf(b1, f.y, acc1[3]);
        f = h2f(u1.z); acc0[4] = fmaf(a1, f.x, acc0[4]); acc1[4] = fmaf(b1, f.x, acc1[4]);
                       acc0[5] = fmaf(a1, f.y, acc0[5]); acc1[5] = fmaf(b1, f.y, acc1[5]);
        f = h2f(u1.w); acc0[6] = fmaf(a1, f.x, acc0[6]); acc1[6] = fmaf(b1, f.x, acc1[6]);
                       acc0[7] = fmaf(a1, f.y, acc0[7]); acc1[7] = fmaf(b1, f.y, acc1[7]);
        f = h2f(u2.x); acc0[0] = fmaf(a2, f.x, acc0[0]); acc1[0] = fmaf(b2, f.x, acc1[0]);
                       acc0[1] = fmaf(a2, f.y, acc0[1]); acc1[1] = fmaf(b2, f.y, acc1[1]);
        f = h2f(u2.y); acc0[2] = fmaf(a2, f.x, acc0[2]); acc1[2] = fmaf(b2, f.x, acc1[2]);
                       acc0[3] = fmaf(a2, f.y, acc0[3]); acc1[3] = fmaf(b2, f.y, acc1[3]);
        f = h2f(u2.z); acc0[4] = fmaf(a2, f.x, acc0[4]); acc1[4] = fmaf(b2, f.x, acc1[4]);
                       acc0[5] = fmaf(a2, f.y, acc0[5]); acc1[5] = fmaf(b2, f.y, acc1[5]);
        f = h2f(u2.w); acc0[6] = fmaf(a2, f.x, acc0[6]); acc1[6] = fmaf(b2, f.x, acc1[6]);
                       acc0[7] = fmaf(a2, f.y, acc0[7]); acc1[7] = fmaf(b2, f.y, acc1[7]);
        f = h2f(u3.x); acc0[0] = fmaf(a3, f.x, acc0[0]); acc1[0] = fmaf(b3, f.x, acc1[0]);
                       acc0[1] = fmaf(a3, f.y, acc0[1]); acc1[1] = fmaf(b3, f.y, acc1[1]);
        f = h2f(u3.y); acc0[2] = fmaf(a3, f.x, acc0[2]); acc1[2] = fmaf(b3, f.x, acc1[2]);
                       acc0[3] = fmaf(a3, f.y, acc0[3]); acc1[3] = fmaf(b3, f.y, acc1[3]);
        f = h2f(u3.z); acc0[4] = fmaf(a3, f.x, acc0[4]); acc1[4] = fmaf(b3, f.x, acc1[4]);
                       acc0[5] = fmaf(a3, f.y, acc0[5]); acc1[5] = fmaf(b3, f.y, acc1[5]);
        f = h2f(u3.w); acc0[6] = fmaf(a3, f.x, acc0[6]); acc1[6] = fmaf(b3, f.x, acc1[6]);
                       acc0[7] = fmaf(a3, f.y, acc0[7]); acc1[7] = fmaf(b3, f.y, acc1[7]);
    }

    #pragma unroll
    for (int i = 0; i < 8; ++i) {
        tile[lj0    ][(sub << 3) + i] = acc0[i];
        tile[lj0 + 1][(sub << 3) + i] = acc1[i];
    }
    __syncthreads();

    // write phase: two 64-row stripes, coalesced + bias
    #pragma unroll
    for (int half = 0; half < 2; ++half) {
        const int lr = (half << 6) + lane;
        const int rc = r0 + lr;
        if (rc < OUT_F) {
            const float bv = bias[rc];
            for (int bb = w; bb < 64; bb += 8)
                out[(size_t)bb * OUT_F + rc] = tile[lr][bb] + bv;
        }
    }
}

// ---------------------------------------------------------------------------
// Fallback (insufficient ws): gather from native x layout. Correct, slow.
// ---------------------------------------------------------------------------
__global__ __launch_bounds__(256) void k_spmm_fallback(
    const float* __restrict__ x,
    const float* __restrict__ vals,
    const int*   __restrict__ rows,
    const int*   __restrict__ cols,
    const float* __restrict__ bias,
    float* __restrict__ out) {
    __shared__ int   rstart[65];
    __shared__ float tile[64][65];
    const int r0   = blockIdx.x * 64;
    const int t    = threadIdx.x;
    const int lane = t & 63;
    const int w    = t >> 6;
    if (t < 65) {
        const int target = r0 + t;
        int lo = 0, hi = NNZ_N;
        while (lo < hi) {
            const int mid = (lo + hi) >> 1;
            if (rows[mid] < target) lo = mid + 1; else hi = mid;
        }
        rstart[t] = lo;
    }
    __syncthreads();
    for (int j = w; j < 64; j += 4) {
        const int s = rstart[j], e = rstart[j + 1];
        float acc = 0.f;
        const size_t base = (size_t)lane * IN_F;
        for (int idx = s; idx < e; ++idx)
            acc = fmaf(vals[idx], x[base + cols[idx]], acc);
        tile[j][lane] = acc;
    }
    __syncthreads();
    const int c = lane;
    if (r0 + c < OUT_F) {
        const float bv = bias[r0 + c];
        for (int bb = w; bb < 64; bb += 4)
            out[(size_t)bb * OUT_F + (r0 + c)] = tile[c][bb] + bv;
    }
}

extern "C" void kernel_launch(void* const* d_in, const int* in_sizes, int n_in,
                              void* d_out, int out_size, void* d_ws, size_t ws_size,
                              hipStream_t stream) {
    const float* x      = (const float*)d_in[0];
    const float* values = (const float*)d_in[1];
    const float* bias   = (const float*)d_in[2];
    const int*   rows   = (const int*)d_in[3];
    const int*   cols   = (const int*)d_in[4];
    float*       out    = (float*)d_out;

    const size_t xh_bytes = (size_t)IN_F * 32 * sizeof(unsigned);   // 12.8 MB
    const size_t rs_off   = (xh_bytes + 255) & ~(size_t)255;
    const size_t rs_bytes = (size_t)(OUT_F + 1) * sizeof(int);
    const size_t pr_off   = (rs_off + rs_bytes + 255) & ~(size_t)255;
    const size_t need     = pr_off + (size_t)NNZ_N * sizeof(uint2); // ~26 MB

    const int row_blocks = (OUT_F + 127) / 128;   // 782

    if (ws_size >= need) {
        unsigned* xh     = (unsigned*)d_ws;
        int*      rstart = (int*)((char*)d_ws + rs_off);
        uint2*    pairs  = (uint2*)((char*)d_ws + pr_off);
        k_prep<<<TBLK + SBLK, 256, 0, stream>>>(x, rows, cols, values, xh, rstart, pairs);
        k_spmm<<<row_blocks, 512, 0, stream>>>(
            (const uint4*)xh, pairs, rstart, bias, out);
    } else {
        k_spmm_fallback<<<(OUT_F + 63) / 64, 256, 0, stream>>>(
            x, values, rows, cols, bias, out);
    }
}

// Round 9
// 131.670 us; speedup vs baseline: 1.0682x; 1.0255x over previous
//
#include <hip/hip_runtime.h>
#include <hip/hip_fp16.h>

#define IN_F   100000
#define OUT_F  100000
#define NNZ_N  1600000
#define TC     256
#define TBLK   ((IN_F + TC - 1) / TC)      // 391 transpose blocks
#define SBLK   ((NNZ_N + 255) / 256)       // 6250 scan/pack blocks

__device__ __forceinline__ float2 h2f(unsigned u) {
    const __half2 h = *reinterpret_cast<const __half2*>(&u);
    return __half22float2(h);
}

// ---------------------------------------------------------------------------
// Prep (fused): blocks [0,TBLK) transpose x (64,IN) f32 -> xh (IN,64) f16
// (u32 index: col*32 + pair). Blocks [TBLK,TBLK+SBLK): rowstart linear scan
// over sorted rows + (col,val) -> uint2 pack.
// ---------------------------------------------------------------------------
__global__ __launch_bounds__(256) void k_prep(
    const float* __restrict__ x,
    const int*   __restrict__ rows,
    const int*   __restrict__ cols,
    const float* __restrict__ vals,
    unsigned* __restrict__ xh,
    int*      __restrict__ rstart,
    uint2*    __restrict__ pairs) {
    __shared__ unsigned tile[TC][33];
    const int bid = blockIdx.x;
    const int t   = threadIdx.x;

    if (bid < TBLK) {
        const int i0   = bid * TC;
        const int colr = i0 + t;
        if (colr < IN_F) {
            #pragma unroll 8
            for (int p = 0; p < 32; ++p) {
                const float a = x[(size_t)(2 * p)     * IN_F + colr];
                const float b = x[(size_t)(2 * p + 1) * IN_F + colr];
                const __half2 h = __floats2half2_rn(a, b);
                tile[t][p] = *reinterpret_cast<const unsigned*>(&h);
            }
        }
        __syncthreads();
        const int u  = t & 31;
        const int c8 = t >> 5;
        for (int cc = c8; cc < TC; cc += 8) {
            const int col = i0 + cc;
            if (col < IN_F)
                xh[(size_t)col * 32 + u] = tile[cc][u];
        }
    } else {
        const int e = (bid - TBLK) * 256 + t;
        if (e >= NNZ_N) return;
        const int cur  = rows[e];
        const int prev = (e == 0) ? -1 : rows[e - 1];
        for (int r = prev + 1; r <= cur; ++r) rstart[r] = e;
        if (e == NNZ_N - 1)
            for (int r = cur + 1; r <= OUT_F; ++r) rstart[r] = NNZ_N;
        pairs[e] = make_uint2((unsigned)cols[e], __float_as_uint(vals[e]));
    }
}

// ---------------------------------------------------------------------------
// SpMM (R5 structure — measured best): block = 512 threads = 8 waves = 64
// rows. Each 8-lane group owns ONE row; lane sub in [0,8) loads uint4 = 8
// halves = batches 8sub..8sub+7. One wave-instruction = 8 distinct edges =
// 8 cache lines; unroll-4 -> 32 lines in flight per wave. fp32 accumulate.
// ---------------------------------------------------------------------------
__global__ __launch_bounds__(512, 4) void k_spmm(
    const uint4* __restrict__ xh4,        // col*8 + sub
    const uint2* __restrict__ pairs,
    const int*   __restrict__ rstart_g,
    const float* __restrict__ bias,
    float* __restrict__ out) {
    __shared__ int   rs[65];
    __shared__ float tile[64][65];
    const int r0   = blockIdx.x * 64;
    const int t    = threadIdx.x;
    const int lane = t & 63;
    const int w    = t >> 6;

    if (t < 65) {
        int idx = r0 + t; if (idx > OUT_F) idx = OUT_F;
        rs[t] = rstart_g[idx];
    }
    __syncthreads();

    const int g   = lane >> 3;            // group -> local row
    const int sub = lane & 7;             // batch octet
    const int lj  = (w << 3) + g;
    const int s   = rs[lj];
    const int e   = rs[lj + 1];

    float acc[8];
    #pragma unroll
    for (int i = 0; i < 8; ++i) acc[i] = 0.f;

    for (int base = s; base < e; base += 4) {
        const int e1 = e - 1;
        const int i1 = (base + 1 < e) ? base + 1 : e1;
        const int i2 = (base + 2 < e) ? base + 2 : e1;
        const int i3 = (base + 3 < e) ? base + 3 : e1;
        const uint2 p0 = pairs[base];
        const uint2 p1 = pairs[i1];
        const uint2 p2 = pairs[i2];
        const uint2 p3 = pairs[i3];
        const float v0 = __uint_as_float(p0.y);
        const float v1 = (base + 1 < e) ? __uint_as_float(p1.y) : 0.f;
        const float v2 = (base + 2 < e) ? __uint_as_float(p2.y) : 0.f;
        const float v3 = (base + 3 < e) ? __uint_as_float(p3.y) : 0.f;
        const uint4 u0 = xh4[(size_t)p0.x * 8 + sub];
        const uint4 u1 = xh4[(size_t)p1.x * 8 + sub];
        const uint4 u2 = xh4[(size_t)p2.x * 8 + sub];
        const uint4 u3 = xh4[(size_t)p3.x * 8 + sub];
        float2 f;
        f = h2f(u0.x); acc[0] = fmaf(v0, f.x, acc[0]); acc[1] = fmaf(v0, f.y, acc[1]);
        f = h2f(u0.y); acc[2] = fmaf(v0, f.x, acc[2]); acc[3] = fmaf(v0, f.y, acc[3]);
        f = h2f(u0.z); acc[4] = fmaf(v0, f.x, acc[4]); acc[5] = fmaf(v0, f.y, acc[5]);
        f = h2f(u0.w); acc[6] = fmaf(v0, f.x, acc[6]); acc[7] = fmaf(v0, f.y, acc[7]);
        f = h2f(u1.x); acc[0] = fmaf(v1, f.x, acc[0]); acc[1] = fmaf(v1, f.y, acc[1]);
        f = h2f(u1.y); acc[2] = fmaf(v1, f.x, acc[2]); acc[3] = fmaf(v1, f.y, acc[3]);
        f = h2f(u1.z); acc[4] = fmaf(v1, f.x, acc[4]); acc[5] = fmaf(v1, f.y, acc[5]);
        f = h2f(u1.w); acc[6] = fmaf(v1, f.x, acc[6]); acc[7] = fmaf(v1, f.y, acc[7]);
        f = h2f(u2.x); acc[0] = fmaf(v2, f.x, acc[0]); acc[1] = fmaf(v2, f.y, acc[1]);
        f = h2f(u2.y); acc[2] = fmaf(v2, f.x, acc[2]); acc[3] = fmaf(v2, f.y, acc[3]);
        f = h2f(u2.z); acc[4] = fmaf(v2, f.x, acc[4]); acc[5] = fmaf(v2, f.y, acc[5]);
        f = h2f(u2.w); acc[6] = fmaf(v2, f.x, acc[6]); acc[7] = fmaf(v2, f.y, acc[7]);
        f = h2f(u3.x); acc[0] = fmaf(v3, f.x, acc[0]); acc[1] = fmaf(v3, f.y, acc[1]);
        f = h2f(u3.y); acc[2] = fmaf(v3, f.x, acc[2]); acc[3] = fmaf(v3, f.y, acc[3]);
        f = h2f(u3.z); acc[4] = fmaf(v3, f.x, acc[4]); acc[5] = fmaf(v3, f.y, acc[5]);
        f = h2f(u3.w); acc[6] = fmaf(v3, f.x, acc[6]); acc[7] = fmaf(v3, f.y, acc[7]);
    }

    // tile[lj][8sub+i]: 2 lanes/bank = free
    #pragma unroll
    for (int i = 0; i < 8; ++i) tile[lj][(sub << 3) + i] = acc[i];
    __syncthreads();

    const int rc = r0 + lane;
    if (rc < OUT_F) {
        const float bv = bias[rc];
        for (int bb = w; bb < 64; bb += 8)
            out[(size_t)bb * OUT_F + rc] = tile[lane][bb] + bv;
    }
}

// ---------------------------------------------------------------------------
// Fallback (insufficient ws): gather from native x layout. Correct, slow.
// ---------------------------------------------------------------------------
__global__ __launch_bounds__(256) void k_spmm_fallback(
    const float* __restrict__ x,
    const float* __restrict__ vals,
    const int*   __restrict__ rows,
    const int*   __restrict__ cols,
    const float* __restrict__ bias,
    float* __restrict__ out) {
    __shared__ int   rstart[65];
    __shared__ float tile[64][65];
    const int r0   = blockIdx.x * 64;
    const int t    = threadIdx.x;
    const int lane = t & 63;
    const int w    = t >> 6;
    if (t < 65) {
        const int target = r0 + t;
        int lo = 0, hi = NNZ_N;
        while (lo < hi) {
            const int mid = (lo + hi) >> 1;
            if (rows[mid] < target) lo = mid + 1; else hi = mid;
        }
        rstart[t] = lo;
    }
    __syncthreads();
    for (int j = w; j < 64; j += 4) {
        const int s = rstart[j], e = rstart[j + 1];
        float acc = 0.f;
        const size_t base = (size_t)lane * IN_F;
        for (int idx = s; idx < e; ++idx)
            acc = fmaf(vals[idx], x[base + cols[idx]], acc);
        tile[j][lane] = acc;
    }
    __syncthreads();
    const int c = lane;
    if (r0 + c < OUT_F) {
        const float bv = bias[r0 + c];
        for (int bb = w; bb < 64; bb += 4)
            out[(size_t)bb * OUT_F + (r0 + c)] = tile[c][bb] + bv;
    }
}

extern "C" void kernel_launch(void* const* d_in, const int* in_sizes, int n_in,
                              void* d_out, int out_size, void* d_ws, size_t ws_size,
                              hipStream_t stream) {
    const float* x      = (const float*)d_in[0];
    const float* values = (const float*)d_in[1];
    const float* bias   = (const float*)d_in[2];
    const int*   rows   = (const int*)d_in[3];
    const int*   cols   = (const int*)d_in[4];
    float*       out    = (float*)d_out;

    const size_t xh_bytes = (size_t)IN_F * 32 * sizeof(unsigned);   // 12.8 MB
    const size_t rs_off   = (xh_bytes + 255) & ~(size_t)255;
    const size_t rs_bytes = (size_t)(OUT_F + 1) * sizeof(int);
    const size_t pr_off   = (rs_off + rs_bytes + 255) & ~(size_t)255;
    const size_t need     = pr_off + (size_t)NNZ_N * sizeof(uint2); // ~26 MB

    const int row_blocks = (OUT_F + 63) / 64;   // 1563

    if (ws_size >= need) {
        unsigned* xh     = (unsigned*)d_ws;
        int*      rstart = (int*)((char*)d_ws + rs_off);
        uint2*    pairs  = (uint2*)((char*)d_ws + pr_off);
        k_prep<<<TBLK + SBLK, 256, 0, stream>>>(x, rows, cols, values, xh, rstart, pairs);
        k_spmm<<<row_blocks, 512, 0, stream>>>(
            (const uint4*)xh, pairs, rstart, bias, out);
    } else {
        k_spmm_fallback<<<row_blocks, 256, 0, stream>>>(x, values, rows, cols, bias, out);
    }
}